// Round 3
// baseline (283.883 us; speedup 1.0000x reference)
//
#include <hip/hip_runtime.h>

// GRU autoregressive decoder, bf16-MFMA persistent-weight, 8-wave blocks.
// B=16384, I=32, H=128, 30 steps, x0 = x[:,30,:], y feeds back as x.
//
// Round 6 -> 7 changes (occupancy: 2 independent blocks per CU):
//  * BM 64->32, grid 256->512 => 2 blocks/CU. Round 6's counters showed no
//    pipe >50% busy with 1 block/CU: every per-step barrier/latency stall
//    idles the whole CU. A second independent block fills those stalls.
//  * To make 2 blocks fit WITHOUT round 5's spill disaster (demand ~160 vs
//    128-reg cap -> 49MB FETCH of scratch):
//      - Wout B-fragments live in LDS (written once by waves 0-1, read back
//        per step by waves 0-3) -> frees 16 VGPRs.
//      - A-fragments loaded per-kt inside the MFMA loop (not 4 up front).
//      - BM=32 halves lane-private h-state to 8 regs.
//    Steady live set ~= 64 (r/z/nh/ni frags) + 8 (hst) + ~40 transient ~= 115,
//    so __launch_bounds__(512,4) (128-reg cap) holds spill-free.
//  * HBS reverted 136->144: the 136 experiment INCREASED bank conflicts
//    (2.99M -> 4.99M measured).
//  * Keeps round 6's folded recurrence (x-GEMM folded into K=128 h-GEMM via
//    precomputed Wstar/bstar in d_ws) and ONE barrier per step.
//
// Steady step, per wave: phase2 (waves 0-3): 4 MFMA y-tile; phase1: 2 m-tiles
// x 16 MFMA (4 K-tiles x {r,z,nh,ni}) + activations on 8 elems/lane.

#define NB    16384
#define TT    60
#define II    32
#define HH    128
#define NSTEP 30
#define SEQ0  30
#define BM    32
#define HBS   144   // bf16 h-row stride: 288B rows (72 dwords)
#define XBS   40    // bf16 x-row stride: 80B rows (step-0 x0 only)

// d_ws layout (floats): Wstar[384][128] at 0, bstar[384] at 49152.
#define WS_WSTAR 0
#define WS_BSTAR (384 * 128)

typedef __attribute__((ext_vector_type(8))) short bf16x8;
typedef __attribute__((ext_vector_type(4))) float f32x4;

#define MFMA(a, b, c) __builtin_amdgcn_mfma_f32_16x16x32_bf16((a), (b), (c), 0, 0, 0)

__device__ __forceinline__ short f2bf(float x) {  // RNE fp32->bf16
    unsigned u = __float_as_uint(x);
    u += 0x7FFFu + ((u >> 16) & 1u);
    return (short)(u >> 16);
}
__device__ __forceinline__ bf16x8 ldw8(const float* p) {  // 8 fp32 -> bf16x8
    float4 a = *(const float4*)p;
    float4 b = *(const float4*)(p + 4);
    bf16x8 f;
    f[0] = f2bf(a.x); f[1] = f2bf(a.y); f[2] = f2bf(a.z); f[3] = f2bf(a.w);
    f[4] = f2bf(b.x); f[5] = f2bf(b.y); f[6] = f2bf(b.z); f[7] = f2bf(b.w);
    return f;
}
// v_rcp_f32-based activations: 1 inst instead of the ~10-inst IEEE divide.
__device__ __forceinline__ float sigm(float a) {
    return __builtin_amdgcn_rcpf(1.0f + __expf(-a));
}
__device__ __forceinline__ float tanh_(float a) {
    return 1.0f - 2.0f * __builtin_amdgcn_rcpf(1.0f + __expf(2.0f * a));
}

// ---- prep: Wstar[jg][k] = (gate<2 ? Whh[jg][k] : 0) + sum_i Wih[jg][i]*Wout[i][k]
//      bstar[jg]  = bih[jg] + (gate<2 ? bhh[jg] : 0) + sum_i Wih[jg][i]*bout[i]
__global__ void fold_kernel(const float* __restrict__ Wih,
                            const float* __restrict__ Whh,
                            const float* __restrict__ bih,
                            const float* __restrict__ bhh,
                            const float* __restrict__ Wout,
                            const float* __restrict__ bout,
                            float* __restrict__ ws)
{
    const int jg = blockIdx.x;     // 0..383 = gate*128 + j
    const int k  = threadIdx.x;    // 0..127
    const int gate = jg >> 7;
    float acc  = (gate < 2) ? Whh[(size_t)jg * HH + k] : 0.0f;
    float bacc = 0.0f;
    #pragma unroll 8
    for (int i = 0; i < II; ++i) {
        const float w = Wih[(size_t)jg * II + i];
        acc  += w * Wout[(size_t)i * HH + k];
        bacc += w * bout[i];
    }
    ws[WS_WSTAR + (size_t)jg * HH + k] = acc;
    if (k == 0)
        ws[WS_BSTAR + jg] = bih[jg] + ((gate < 2) ? bhh[jg] : 0.0f) + bacc;
}

__global__ __launch_bounds__(512, 4)
void gru_mfma_kernel(const float* __restrict__ x,
                     const float* __restrict__ h0,
                     const float* __restrict__ Wih,
                     const float* __restrict__ Whh,
                     const float* __restrict__ bih,
                     const float* __restrict__ bhh,
                     const float* __restrict__ Wout,
                     const float* __restrict__ bout,
                     const float* __restrict__ ws,
                     float* __restrict__ out)
{
    __shared__ short shb[2][BM * HBS];  // bf16 h, double-buffered (18.4 KB)
    __shared__ short sxb[BM * XBS];     // bf16 x0 (step 0 only, 2.5 KB)
    __shared__ short sWo[2 * 4 * 64 * 8];  // Wout B-frags, 8 KB:
                                           // slot ((ct*4+kt)*64+lane)*8

    const int tid    = threadIdx.x;
    const int lane   = tid & 63;
    const int wave   = __builtin_amdgcn_readfirstlane(tid >> 6);  // 0..7
    const int n16    = lane & 15;   // MFMA col / A-row index
    const int quad   = lane >> 4;   // MFMA k-group / D-row group
    const int rowblk = blockIdx.x * BM;
    const int j      = wave * 16 + n16;   // hidden unit this lane's gate col

    // ---- persistent n-gate h-weights (used by ALL steps) ----
    bf16x8 Bnh[4];
    float  b_nh;
    {
        const float* wn = Whh + (size_t)(2 * HH + j) * HH;
        #pragma unroll
        for (int kt = 0; kt < 4; ++kt)
            Bnh[kt] = ldw8(wn + kt * 32 + quad * 8);
        b_nh = bhh[2 * HH + j];
    }
    // ---- phase-2 tile assignment; Wout frags staged to LDS by waves 0-1 ----
    const int rowtile = wave >> 1;    // 0/1: which 16 rows of the 32
    const int coltile = wave & 1;     // 0/1: which 16 output cols
    float b_o = 0.0f;
    if (wave < 2) {                   // wave w stages coltile=w's fragments
        #pragma unroll
        for (int kt = 0; kt < 4; ++kt) {
            bf16x8 t = ldw8(Wout + (size_t)(wave * 16 + n16) * HH + kt * 32 + quad * 8);
            *(bf16x8*)&sWo[((wave * 4 + kt) * 64 + lane) * 8] = t;
        }
    }
    if (wave < 4) b_o = bout[coltile * 16 + n16];

    // ---- lane-private fp32 h-state: slot (mt,reg) = h[row][col],
    //      row = mt*16 + quad*4 + reg, col = j ----
    float hst[2][4];
    #pragma unroll
    for (int mt = 0; mt < 2; ++mt)
        #pragma unroll
        for (int reg = 0; reg < 4; ++reg)
            hst[mt][reg] = h0[(size_t)(rowblk + mt * 16 + quad * 4 + reg) * HH + j];

    // ---- stage bf16 h0 and x0 into LDS (one-time, cooperative) ----
    {
        const int r  = tid >> 4;            // 32 rows, 16 threads/row
        const int c0 = (tid & 15) * 8;      // 8 cols each
        *(bf16x8*)&shb[0][r * HBS + c0] = ldw8(h0 + (size_t)(rowblk + r) * HH + c0);
    }
    if (tid < 128) {
        const int r  = tid >> 2;            // 32 rows, 4 threads/row
        const int c0 = (tid & 3) * 8;
        *(bf16x8*)&sxb[r * XBS + c0] = ldw8(x + ((size_t)(rowblk + r) * TT + SEQ0) * II + c0);
    }
    __syncthreads();

    // ================= peeled step 0: un-folded weights + real x0 =========
    {
        bf16x8 Br0[4], Bz0[4], Bxr, Bxz, Bxn;
        const float* wr = Whh + (size_t)j * HH;
        const float* wz = Whh + (size_t)(HH + j) * HH;
        #pragma unroll
        for (int kt = 0; kt < 4; ++kt) {
            Br0[kt] = ldw8(wr + kt * 32 + quad * 8);
            Bz0[kt] = ldw8(wz + kt * 32 + quad * 8);
        }
        Bxr = ldw8(Wih + (size_t)j * II + quad * 8);
        Bxz = ldw8(Wih + (size_t)(HH + j) * II + quad * 8);
        Bxn = ldw8(Wih + (size_t)(2 * HH + j) * II + quad * 8);
        const float b_r0 = bih[j] + bhh[j];
        const float b_z0 = bih[HH + j] + bhh[HH + j];
        const float b_n0 = bih[2 * HH + j];

        #pragma unroll
        for (int mt = 0; mt < 2; ++mt) {
            f32x4 ar  = (f32x4){b_r0, b_r0, b_r0, b_r0};
            f32x4 az  = (f32x4){b_z0, b_z0, b_z0, b_z0};
            f32x4 anh = (f32x4){b_nh, b_nh, b_nh, b_nh};
            f32x4 anx = (f32x4){b_n0, b_n0, b_n0, b_n0};
            #pragma unroll
            for (int kt = 0; kt < 4; ++kt) {
                bf16x8 A = *(const bf16x8*)&shb[0][(mt * 16 + n16) * HBS + kt * 32 + quad * 8];
                ar  = MFMA(A, Br0[kt], ar);
                az  = MFMA(A, Bz0[kt], az);
                anh = MFMA(A, Bnh[kt], anh);
            }
            {
                bf16x8 Ax = *(const bf16x8*)&sxb[(mt * 16 + n16) * XBS + quad * 8];
                ar  = MFMA(Ax, Bxr, ar);
                az  = MFMA(Ax, Bxz, az);
                anx = MFMA(Ax, Bxn, anx);
            }
            #pragma unroll
            for (int reg = 0; reg < 4; ++reg) {
                const float r = sigm(ar[reg]);
                const float z = sigm(az[reg]);
                const float n = tanh_(anx[reg] + r * anh[reg]);
                const float hnew = n + z * (hst[mt][reg] - n);
                hst[mt][reg] = hnew;
                shb[1][(mt * 16 + quad * 4 + reg) * HBS + j] = f2bf(hnew);
            }
        }
    }

    // ---- folded steady-state weights (from ws; step-0 regs now dead) ----
    bf16x8 Brs[4], Bzs[4], Bni[4];
    float  b_rs, b_zs, b_ni;
    {
        const float* pr = ws + WS_WSTAR + (size_t)j * HH;
        const float* pz = ws + WS_WSTAR + (size_t)(HH + j) * HH;
        const float* pn = ws + WS_WSTAR + (size_t)(2 * HH + j) * HH;
        #pragma unroll
        for (int kt = 0; kt < 4; ++kt) {
            Brs[kt] = ldw8(pr + kt * 32 + quad * 8);
            Bzs[kt] = ldw8(pz + kt * 32 + quad * 8);
            Bni[kt] = ldw8(pn + kt * 32 + quad * 8);
        }
        b_rs = ws[WS_BSTAR + j];
        b_zs = ws[WS_BSTAR + HH + j];
        b_ni = ws[WS_BSTAR + 2 * HH + j];
    }

    __syncthreads();   // step-0 h' (and sWo) visible to all waves

    // ================= steps 0..29: {phase2(s) || phase1(s+1)} =============
    // Loop-top invariant: barrier passed; shb[q] holds h_{s+1}. Phase 2 reads
    // shb[q]; phase 1 of step s+1 reads shb[q], writes shb[p] — disjoint, so
    // ONE barrier per step.
    int p = 0;
    for (int s = 0; s < NSTEP; ++s) {
        const int q = 1 - p;

        // ---- phase 2 of step s: y = h_{s+1} @ Wout^T + bout (waves 0-3) ----
        if (wave < 4) {
            f32x4 yo = (f32x4){b_o, b_o, b_o, b_o};
            #pragma unroll
            for (int kt = 0; kt < 4; ++kt) {
                bf16x8 A2  = *(const bf16x8*)&shb[q][(rowtile * 16 + n16) * HBS + kt * 32 + quad * 8];
                bf16x8 Bof = *(const bf16x8*)&sWo[((coltile * 4 + kt) * 64 + lane) * 8];
                yo = MFMA(A2, Bof, yo);
            }
            #pragma unroll
            for (int reg = 0; reg < 4; ++reg) {
                const int r_l = rowtile * 16 + quad * 4 + reg;
                out[(size_t)(rowblk + r_l) * (NSTEP * II) + s * II + coltile * 16 + n16] = yo[reg];
            }
        }

        if (s == NSTEP - 1) break;   // last y written; no more recurrence

        // ---- phase 1 of step s+1: gates + h update (folded, K=128) ----
        #pragma unroll
        for (int mt = 0; mt < 2; ++mt) {
            f32x4 ar  = (f32x4){b_rs, b_rs, b_rs, b_rs};
            f32x4 az  = (f32x4){b_zs, b_zs, b_zs, b_zs};
            f32x4 anh = (f32x4){b_nh, b_nh, b_nh, b_nh};
            f32x4 ani = (f32x4){b_ni, b_ni, b_ni, b_ni};
            #pragma unroll
            for (int kt = 0; kt < 4; ++kt) {       // 4 indep acc chains
                bf16x8 A = *(const bf16x8*)&shb[q][(mt * 16 + n16) * HBS + kt * 32 + quad * 8];
                ar  = MFMA(A, Brs[kt], ar);
                az  = MFMA(A, Bzs[kt], az);
                anh = MFMA(A, Bnh[kt], anh);
                ani = MFMA(A, Bni[kt], ani);
            }
            #pragma unroll
            for (int reg = 0; reg < 4; ++reg) {
                const float r = sigm(ar[reg]);
                const float z = sigm(az[reg]);
                const float n = tanh_(ani[reg] + r * anh[reg]);
                const float hnew = n + z * (hst[mt][reg] - n);
                hst[mt][reg] = hnew;
                shb[p][(mt * 16 + quad * 4 + reg) * HBS + j] = f2bf(hnew);
            }
        }

        p = q;             // next step reads the buffer just written
        __syncthreads();   // ONE barrier per step: h' exchange
    }
}

extern "C" void kernel_launch(void* const* d_in, const int* in_sizes, int n_in,
                              void* d_out, int out_size, void* d_ws, size_t ws_size,
                              hipStream_t stream) {
    (void)in_sizes; (void)n_in; (void)out_size; (void)ws_size;
    const float* x    = (const float*)d_in[0];
    const float* h0   = (const float*)d_in[1];
    const float* Wih  = (const float*)d_in[2];
    const float* Whh  = (const float*)d_in[3];
    const float* bih  = (const float*)d_in[4];
    const float* bhh  = (const float*)d_in[5];
    const float* Wout = (const float*)d_in[6];
    const float* bout = (const float*)d_in[7];
    float* out = (float*)d_out;
    float* ws  = (float*)d_ws;

    fold_kernel<<<dim3(384), dim3(128), 0, stream>>>(Wih, Whh, bih, bhh,
                                                     Wout, bout, ws);
    dim3 grid(NB / BM);   // 512 blocks -> 2 per CU (16 waves = 4 waves/SIMD)
    dim3 block(512);
    gru_mfma_kernel<<<grid, block, 0, stream>>>(x, h0, Wih, Whh, bih, bhh,
                                                Wout, bout, ws, out);
}

// Round 4
// 281.768 us; speedup vs baseline: 1.0075x; 1.0075x over previous
//
#include <hip/hip_runtime.h>

// GRU autoregressive decoder, bf16-MFMA persistent-weight, 8-wave blocks.
// B=16384, I=32, H=128, 30 steps, x0 = x[:,30,:], y feeds back as x.
//
// Round 7 -> 8 changes:
//  * __launch_bounds__(512,4) -> (512,2). Evidence across rounds: (512,2)
//    compiles to 104-108 VGPRs (cap 128), (512,4) compiles to 64 VGPRs +
//    scratch spill (FETCH 31MB, WRITE 108MB). This hipcc treats the 2nd arg
//    as min BLOCKS/CU (CUDA semantics): arg=4 -> 8 waves/SIMD -> 64-reg cap.
//    arg=2 -> 4 waves/SIMD -> 128-reg cap, which the slim kernel fits.
//    Grid stays 512 (BM=32) => 2 blocks/CU, 16 waves/CU, NO spill.
//  * In-loop __syncthreads() -> "s_waitcnt lgkmcnt(0); s_barrier" inline asm
//    (+ sched_barrier(0) pin). __syncthreads drains vmcnt(0) too, which
//    serializes each step on the ACK of the scattered out[] stores (~300-500
//    cyc). No one reads out; the only in-loop hazard is the LDS h' exchange.
//  * Keeps: folded recurrence (x-GEMM folded into K=128 via Wstar/bstar in
//    d_ws), one barrier/step, Wout frags in LDS, per-kt A loads, HBS=144,
//    rcp-based activations.

#define NB    16384
#define TT    60
#define II    32
#define HH    128
#define NSTEP 30
#define SEQ0  30
#define BM    32
#define HBS   144   // bf16 h-row stride: 288B rows (72 dwords)
#define XBS   40    // bf16 x-row stride: 80B rows (step-0 x0 only)

// d_ws layout (floats): Wstar[384][128] at 0, bstar[384] at 49152.
#define WS_WSTAR 0
#define WS_BSTAR (384 * 128)

typedef __attribute__((ext_vector_type(8))) short bf16x8;
typedef __attribute__((ext_vector_type(4))) float f32x4;

#define MFMA(a, b, c) __builtin_amdgcn_mfma_f32_16x16x32_bf16((a), (b), (c), 0, 0, 0)

// LDS-only barrier: wait DS ops, sync, and pin the scheduler so following
// ds_reads/MFMAs don't hoist above it (guide rule #18).
#define LDS_BARRIER() do {                                        \
    asm volatile("s_waitcnt lgkmcnt(0)\n\ts_barrier" ::: "memory"); \
    __builtin_amdgcn_sched_barrier(0);                            \
} while (0)

__device__ __forceinline__ short f2bf(float x) {  // RNE fp32->bf16
    unsigned u = __float_as_uint(x);
    u += 0x7FFFu + ((u >> 16) & 1u);
    return (short)(u >> 16);
}
__device__ __forceinline__ bf16x8 ldw8(const float* p) {  // 8 fp32 -> bf16x8
    float4 a = *(const float4*)p;
    float4 b = *(const float4*)(p + 4);
    bf16x8 f;
    f[0] = f2bf(a.x); f[1] = f2bf(a.y); f[2] = f2bf(a.z); f[3] = f2bf(a.w);
    f[4] = f2bf(b.x); f[5] = f2bf(b.y); f[6] = f2bf(b.z); f[7] = f2bf(b.w);
    return f;
}
// v_rcp_f32-based activations: 1 inst instead of the ~10-inst IEEE divide.
__device__ __forceinline__ float sigm(float a) {
    return __builtin_amdgcn_rcpf(1.0f + __expf(-a));
}
__device__ __forceinline__ float tanh_(float a) {
    return 1.0f - 2.0f * __builtin_amdgcn_rcpf(1.0f + __expf(2.0f * a));
}

// ---- prep: Wstar[jg][k] = (gate<2 ? Whh[jg][k] : 0) + sum_i Wih[jg][i]*Wout[i][k]
//      bstar[jg]  = bih[jg] + (gate<2 ? bhh[jg] : 0) + sum_i Wih[jg][i]*bout[i]
__global__ void fold_kernel(const float* __restrict__ Wih,
                            const float* __restrict__ Whh,
                            const float* __restrict__ bih,
                            const float* __restrict__ bhh,
                            const float* __restrict__ Wout,
                            const float* __restrict__ bout,
                            float* __restrict__ ws)
{
    const int jg = blockIdx.x;     // 0..383 = gate*128 + j
    const int k  = threadIdx.x;    // 0..127
    const int gate = jg >> 7;
    float acc  = (gate < 2) ? Whh[(size_t)jg * HH + k] : 0.0f;
    float bacc = 0.0f;
    #pragma unroll 8
    for (int i = 0; i < II; ++i) {
        const float w = Wih[(size_t)jg * II + i];
        acc  += w * Wout[(size_t)i * HH + k];
        bacc += w * bout[i];
    }
    ws[WS_WSTAR + (size_t)jg * HH + k] = acc;
    if (k == 0)
        ws[WS_BSTAR + jg] = bih[jg] + ((gate < 2) ? bhh[jg] : 0.0f) + bacc;
}

__global__ __launch_bounds__(512, 2)
void gru_mfma_kernel(const float* __restrict__ x,
                     const float* __restrict__ h0,
                     const float* __restrict__ Wih,
                     const float* __restrict__ Whh,
                     const float* __restrict__ bih,
                     const float* __restrict__ bhh,
                     const float* __restrict__ Wout,
                     const float* __restrict__ bout,
                     const float* __restrict__ ws,
                     float* __restrict__ out)
{
    __shared__ short shb[2][BM * HBS];  // bf16 h, double-buffered (18.4 KB)
    __shared__ short sxb[BM * XBS];     // bf16 x0 (step 0 only, 2.5 KB)
    __shared__ short sWo[2 * 4 * 64 * 8];  // Wout B-frags, 8 KB:
                                           // slot ((ct*4+kt)*64+lane)*8

    const int tid    = threadIdx.x;
    const int lane   = tid & 63;
    const int wave   = __builtin_amdgcn_readfirstlane(tid >> 6);  // 0..7
    const int n16    = lane & 15;   // MFMA col / A-row index
    const int quad   = lane >> 4;   // MFMA k-group / D-row group
    const int rowblk = blockIdx.x * BM;
    const int j      = wave * 16 + n16;   // hidden unit this lane's gate col

    // ---- persistent n-gate h-weights (used by ALL steps) ----
    bf16x8 Bnh[4];
    float  b_nh;
    {
        const float* wn = Whh + (size_t)(2 * HH + j) * HH;
        #pragma unroll
        for (int kt = 0; kt < 4; ++kt)
            Bnh[kt] = ldw8(wn + kt * 32 + quad * 8);
        b_nh = bhh[2 * HH + j];
    }
    // ---- phase-2 tile assignment; Wout frags staged to LDS by waves 0-1 ----
    const int rowtile = wave >> 1;    // 0/1: which 16 rows of the 32
    const int coltile = wave & 1;     // 0/1: which 16 output cols
    float b_o = 0.0f;
    if (wave < 2) {                   // wave w stages coltile=w's fragments
        #pragma unroll
        for (int kt = 0; kt < 4; ++kt) {
            bf16x8 t = ldw8(Wout + (size_t)(wave * 16 + n16) * HH + kt * 32 + quad * 8);
            *(bf16x8*)&sWo[((wave * 4 + kt) * 64 + lane) * 8] = t;
        }
    }
    if (wave < 4) b_o = bout[coltile * 16 + n16];

    // ---- lane-private fp32 h-state: slot (mt,reg) = h[row][col],
    //      row = mt*16 + quad*4 + reg, col = j ----
    float hst[2][4];
    #pragma unroll
    for (int mt = 0; mt < 2; ++mt)
        #pragma unroll
        for (int reg = 0; reg < 4; ++reg)
            hst[mt][reg] = h0[(size_t)(rowblk + mt * 16 + quad * 4 + reg) * HH + j];

    // ---- stage bf16 h0 and x0 into LDS (one-time, cooperative) ----
    {
        const int r  = tid >> 4;            // 32 rows, 16 threads/row
        const int c0 = (tid & 15) * 8;      // 8 cols each
        *(bf16x8*)&shb[0][r * HBS + c0] = ldw8(h0 + (size_t)(rowblk + r) * HH + c0);
    }
    if (tid < 128) {
        const int r  = tid >> 2;            // 32 rows, 4 threads/row
        const int c0 = (tid & 3) * 8;
        *(bf16x8*)&sxb[r * XBS + c0] = ldw8(x + ((size_t)(rowblk + r) * TT + SEQ0) * II + c0);
    }
    __syncthreads();

    // ================= peeled step 0: un-folded weights + real x0 =========
    {
        bf16x8 Br0[4], Bz0[4], Bxr, Bxz, Bxn;
        const float* wr = Whh + (size_t)j * HH;
        const float* wz = Whh + (size_t)(HH + j) * HH;
        #pragma unroll
        for (int kt = 0; kt < 4; ++kt) {
            Br0[kt] = ldw8(wr + kt * 32 + quad * 8);
            Bz0[kt] = ldw8(wz + kt * 32 + quad * 8);
        }
        Bxr = ldw8(Wih + (size_t)j * II + quad * 8);
        Bxz = ldw8(Wih + (size_t)(HH + j) * II + quad * 8);
        Bxn = ldw8(Wih + (size_t)(2 * HH + j) * II + quad * 8);
        const float b_r0 = bih[j] + bhh[j];
        const float b_z0 = bih[HH + j] + bhh[HH + j];
        const float b_n0 = bih[2 * HH + j];

        #pragma unroll
        for (int mt = 0; mt < 2; ++mt) {
            f32x4 ar  = (f32x4){b_r0, b_r0, b_r0, b_r0};
            f32x4 az  = (f32x4){b_z0, b_z0, b_z0, b_z0};
            f32x4 anh = (f32x4){b_nh, b_nh, b_nh, b_nh};
            f32x4 anx = (f32x4){b_n0, b_n0, b_n0, b_n0};
            #pragma unroll
            for (int kt = 0; kt < 4; ++kt) {
                bf16x8 A = *(const bf16x8*)&shb[0][(mt * 16 + n16) * HBS + kt * 32 + quad * 8];
                ar  = MFMA(A, Br0[kt], ar);
                az  = MFMA(A, Bz0[kt], az);
                anh = MFMA(A, Bnh[kt], anh);
            }
            {
                bf16x8 Ax = *(const bf16x8*)&sxb[(mt * 16 + n16) * XBS + quad * 8];
                ar  = MFMA(Ax, Bxr, ar);
                az  = MFMA(Ax, Bxz, az);
                anx = MFMA(Ax, Bxn, anx);
            }
            #pragma unroll
            for (int reg = 0; reg < 4; ++reg) {
                const float r = sigm(ar[reg]);
                const float z = sigm(az[reg]);
                const float n = tanh_(anx[reg] + r * anh[reg]);
                const float hnew = n + z * (hst[mt][reg] - n);
                hst[mt][reg] = hnew;
                shb[1][(mt * 16 + quad * 4 + reg) * HBS + j] = f2bf(hnew);
            }
        }
    }

    // ---- folded steady-state weights (from ws; step-0 regs now dead) ----
    bf16x8 Brs[4], Bzs[4], Bni[4];
    float  b_rs, b_zs, b_ni;
    {
        const float* pr = ws + WS_WSTAR + (size_t)j * HH;
        const float* pz = ws + WS_WSTAR + (size_t)(HH + j) * HH;
        const float* pn = ws + WS_WSTAR + (size_t)(2 * HH + j) * HH;
        #pragma unroll
        for (int kt = 0; kt < 4; ++kt) {
            Brs[kt] = ldw8(pr + kt * 32 + quad * 8);
            Bzs[kt] = ldw8(pz + kt * 32 + quad * 8);
            Bni[kt] = ldw8(pn + kt * 32 + quad * 8);
        }
        b_rs = ws[WS_BSTAR + j];
        b_zs = ws[WS_BSTAR + HH + j];
        b_ni = ws[WS_BSTAR + 2 * HH + j];
    }

    __syncthreads();   // step-0 h' (and sWo) visible to all waves

    // ================= steps 0..29: {phase2(s) || phase1(s+1)} =============
    // Loop-top invariant: barrier passed; shb[q] holds h_{s+1}. Phase 2 reads
    // shb[q]; phase 1 of step s+1 reads shb[q], writes shb[p] — disjoint, so
    // ONE (LDS-only) barrier per step.
    int p = 0;
    for (int s = 0; s < NSTEP; ++s) {
        const int q = 1 - p;

        // ---- phase 2 of step s: y = h_{s+1} @ Wout^T + bout (waves 0-3) ----
        if (wave < 4) {
            f32x4 yo = (f32x4){b_o, b_o, b_o, b_o};
            #pragma unroll
            for (int kt = 0; kt < 4; ++kt) {
                bf16x8 A2  = *(const bf16x8*)&shb[q][(rowtile * 16 + n16) * HBS + kt * 32 + quad * 8];
                bf16x8 Bof = *(const bf16x8*)&sWo[((coltile * 4 + kt) * 64 + lane) * 8];
                yo = MFMA(A2, Bof, yo);
            }
            #pragma unroll
            for (int reg = 0; reg < 4; ++reg) {
                const int r_l = rowtile * 16 + quad * 4 + reg;
                out[(size_t)(rowblk + r_l) * (NSTEP * II) + s * II + coltile * 16 + n16] = yo[reg];
            }
        }

        if (s == NSTEP - 1) break;   // last y written; no more recurrence

        // ---- phase 1 of step s+1: gates + h update (folded, K=128) ----
        #pragma unroll
        for (int mt = 0; mt < 2; ++mt) {
            f32x4 ar  = (f32x4){b_rs, b_rs, b_rs, b_rs};
            f32x4 az  = (f32x4){b_zs, b_zs, b_zs, b_zs};
            f32x4 anh = (f32x4){b_nh, b_nh, b_nh, b_nh};
            f32x4 ani = (f32x4){b_ni, b_ni, b_ni, b_ni};
            #pragma unroll
            for (int kt = 0; kt < 4; ++kt) {       // 4 indep acc chains
                bf16x8 A = *(const bf16x8*)&shb[q][(mt * 16 + n16) * HBS + kt * 32 + quad * 8];
                ar  = MFMA(A, Brs[kt], ar);
                az  = MFMA(A, Bzs[kt], az);
                anh = MFMA(A, Bnh[kt], anh);
                ani = MFMA(A, Bni[kt], ani);
            }
            #pragma unroll
            for (int reg = 0; reg < 4; ++reg) {
                const float r = sigm(ar[reg]);
                const float z = sigm(az[reg]);
                const float n = tanh_(ani[reg] + r * anh[reg]);
                const float hnew = n + z * (hst[mt][reg] - n);
                hst[mt][reg] = hnew;
                shb[p][(mt * 16 + quad * 4 + reg) * HBS + j] = f2bf(hnew);
            }
        }

        p = q;             // next step reads the buffer just written
        LDS_BARRIER();     // one LDS-only barrier per step: h' exchange
                           // (no vmcnt drain -> out[] store acks off the
                           //  critical path)
    }
}

extern "C" void kernel_launch(void* const* d_in, const int* in_sizes, int n_in,
                              void* d_out, int out_size, void* d_ws, size_t ws_size,
                              hipStream_t stream) {
    (void)in_sizes; (void)n_in; (void)out_size; (void)ws_size;
    const float* x    = (const float*)d_in[0];
    const float* h0   = (const float*)d_in[1];
    const float* Wih  = (const float*)d_in[2];
    const float* Whh  = (const float*)d_in[3];
    const float* bih  = (const float*)d_in[4];
    const float* bhh  = (const float*)d_in[5];
    const float* Wout = (const float*)d_in[6];
    const float* bout = (const float*)d_in[7];
    float* out = (float*)d_out;
    float* ws  = (float*)d_ws;

    fold_kernel<<<dim3(384), dim3(128), 0, stream>>>(Wih, Whh, bih, bhh,
                                                     Wout, bout, ws);
    dim3 grid(NB / BM);   // 512 blocks -> 2 blocks/CU (16 waves, 4/SIMD)
    dim3 block(512);
    gru_mfma_kernel<<<grid, block, 0, stream>>>(x, h0, Wih, Whh, bih, bhh,
                                                Wout, bout, ws, out);
}